// Round 11
// baseline (172.342 us; speedup 1.0000x reference)
//
#include <hip/hip_runtime.h>
#include <hip/hip_bf16.h>

#define B_      8
#define N_      8192
#define C_      64
#define H1_     64
#define H2_     128
#define NS      32
#define NPOINT  2048
#define NGROUP  (B_ * NPOINT)          // 16384
#define NXYZ    (B_ * NPOINT * 3)      // 49152
#define GD      10
#define NCP     1024                   // padded cell count (1000 used)

typedef short bf16x8 __attribute__((ext_vector_type(8)));
typedef float f32x4  __attribute__((ext_vector_type(4)));

#define MFMA32 __builtin_amdgcn_mfma_f32_16x16x32_bf16

__device__ inline unsigned short f2bf(float f) {        // HW RTNE cvt
    __hip_bfloat16 h = __float2bfloat16(f);
    return __builtin_bit_cast(unsigned short, h);
}
__device__ inline float bf2f(unsigned short h) {
    unsigned u = ((unsigned)h) << 16;
    return __builtin_bit_cast(float, u);
}

// Row permutation for the W1-output space (L1 rows / L2 k-cols):
// H'[p] = H_nat[n(p)] with n(p) chosen so that lane (cl,kq)'s L1 D-quadrant
// IS its L2 x32 B-fragment: n = (mt>>1)*32 + (rho>>2)*8 + ((mt&1)<<2) + (rho&3).
__device__ __host__ inline int permrow(int p) {
    int mt = p >> 4, rho = p & 15;
    return ((mt >> 1) << 5) + ((rho >> 2) << 3) + ((mt & 1) << 2) + (rho & 3);
}

// ================================================================ K0: grid build (1 block/batch, 1024 thr)
__global__ __launch_bounds__(1024) void grid_kernel(
    const float* __restrict__ xyz,
    int* __restrict__ cellStart,     // [B][NCP+1]
    int* __restrict__ sortedId,      // [B][N]
    float* __restrict__ sortedXyz)   // [B][N][3]
{
    __shared__ int hist[NCP];
    __shared__ int wsum[16];
    int b = blockIdx.x, t = threadIdx.x;
    hist[t] = 0;
    __syncthreads();
    const float* base = xyz + (size_t)b * N_ * 3;
#pragma unroll
    for (int k = 0; k < N_ / 1024; ++k) {
        int i = k * 1024 + t;
        float x = base[i * 3], y = base[i * 3 + 1], z = base[i * 3 + 2];
        int c = (((int)(x * 9.999f)) * GD + (int)(y * 9.999f)) * GD + (int)(z * 9.999f);
        atomicAdd(&hist[c], 1);
    }
    __syncthreads();
    int s = hist[t];
    int lane = t & 63, w = t >> 6;
    int v = s;
    for (int d = 1; d < 64; d <<= 1) {
        int o = __shfl_up(v, d);
        if (lane >= d) v += o;
    }
    if (lane == 63) wsum[w] = v;
    __syncthreads();
    int wofs = 0;
#pragma unroll
    for (int i = 0; i < 16; ++i) wofs += (i < w) ? wsum[i] : 0;
    int excl = wofs + v - s;
    int* cs = cellStart + b * (NCP + 1);
    cs[t] = excl;
    if (t == 1023) cs[NCP] = excl + s;
    __syncthreads();
    hist[t] = excl;
    __syncthreads();
#pragma unroll
    for (int k = 0; k < N_ / 1024; ++k) {
        int i = k * 1024 + t;
        float x = base[i * 3], y = base[i * 3 + 1], z = base[i * 3 + 2];
        int c = (((int)(x * 9.999f)) * GD + (int)(y * 9.999f)) * GD + (int)(z * 9.999f);
        int pos = atomicAdd(&hist[c], 1);
        sortedId[b * N_ + pos] = i;
        float* d = sortedXyz + ((size_t)(b * N_) + pos) * 3;
        d[0] = x; d[1] = y; d[2] = z;
    }
}

// ================================================================ K1: prep
// blocks [0,1024): ftrans  (B,C,N) f32 -> (B,N,C) bf16 (hi only)
// blocks [1024,1048): new_xyz copy (float4)
// blocks [1048,1080): weight prep (hi/lo, MFMA-permuted, W1 rows permrow'd)
__global__ __launch_bounds__(256) void prep_all_kernel(
    const float* __restrict__ xyz, const float* __restrict__ feat,
    const float* __restrict__ W1, const float* __restrict__ W2,
    unsigned short* __restrict__ fT_hi,
    unsigned short* __restrict__ W1x_hi, unsigned short* __restrict__ W1x_lo,
    unsigned short* __restrict__ W2x_hi, unsigned short* __restrict__ W2x_lo,
    float* __restrict__ out)
{
    __shared__ float tile[64][65];
    int blk = blockIdx.x, t = threadIdx.x;

    if (blk < 1024) {
        // ---------------- ftrans (hi plane only)
        int b = blk >> 7, nt = blk & 127;
        int n0 = nt * 64;
        int tx = t & 63, ty = t >> 6;
#pragma unroll
        for (int k = 0; k < 16; ++k) {
            int c = ty * 16 + k;
            tile[c][tx] = feat[((size_t)b * C_ + c) * N_ + n0 + tx];
        }
        __syncthreads();
#pragma unroll
        for (int k = 0; k < 16; ++k) {
            int n = ty * 16 + k;
            float v = tile[tx][n];
            size_t dst = ((size_t)(b * N_ + n0 + n)) * C_ + tx;
            fT_hi[dst] = f2bf(v);
        }
    } else if (blk < 1048) {
        // ---------------- new_xyz copy (float4 granularity)
        const float4* src = reinterpret_cast<const float4*>(xyz);
        float4* dst = reinterpret_cast<float4*>(out);
#pragma unroll
        for (int k = 0; k < 2; ++k) {
            int i4 = (blk - 1024) * 512 + k * 256 + t;      // < 12288
            int b = i4 / 1536, r = i4 - b * 1536;
            dst[i4] = src[b * 6144 + r];
        }
    } else {
        // ---------------- weight prep
        int tg = (blk - 1048) * 256 + t;
        if (tg < 6144) {
            // W1x[(mt*3+kt)*512 + (kq*16+cl)*8 + j] <- W1nat[permrow(mt*16+cl)][k=kt*32+kq*8+j]
            int j = tg & 7, cl = (tg >> 3) & 15, kq = (tg >> 7) & 3, t2 = tg >> 9;
            int kt = t2 % 3, mt = t2 / 3;
            int row = permrow(mt * 16 + cl);
            int k = kt * 32 + kq * 8 + j;
            float wv = 0.f;
            if (k < 64) wv = W1[row * 67 + 3 + k];
            else if (k < 67) wv = W1[row * 67 + (k - 64)];
            unsigned short h = f2bf(wv);
            W1x_hi[tg] = h; W1x_lo[tg] = f2bf(wv - bf2f(h));
        }
        if (tg < 8192) {
            // W2x[(mt2*2+kt)*512 + (kq*16+cl)*8 + j] <- W2[mt2*16+cl][H'-space col kt*32+kq*8+j]
            int j = tg & 7, cl = (tg >> 3) & 15, kq = (tg >> 7) & 3;
            int kt = (tg >> 9) & 1, mt2 = tg >> 10;
            int row = mt2 * 16 + cl, k = kt * 32 + kq * 8 + j;
            float wv = W2[row * 64 + k];
            unsigned short h = f2bf(wv);
            W2x_hi[tg] = h; W2x_lo[tg] = f2bf(wv - bf2f(h));
        }
    }
}

// ================================================================ K2: fused ballq + MLP + maxpool + store
__global__ __launch_bounds__(256) void fused_kernel(
    const float* __restrict__ xyz,
    const int* __restrict__ cellStart,
    const int* __restrict__ sortedId,
    const float* __restrict__ sortedXyz,
    const unsigned short* __restrict__ fT_hi,
    const unsigned short* __restrict__ W1x_hi, const unsigned short* __restrict__ W1x_lo,
    const float* __restrict__ b1,
    const unsigned short* __restrict__ W2x_hi, const unsigned short* __restrict__ W2x_lo,
    const float* __restrict__ b2,
    float* __restrict__ out)
{
    __shared__ int shbuf[4][128];            // hitbuf (per-wave), then ystage
    int t = threadIdx.x;
    int w = t >> 6, lane = t & 63;
    int g = blockIdx.x * 4 + w;
    int b = g >> 11, s = g & 2047;

    // ---------------- ball query ----------------
    const float* qp = xyz + ((size_t)(b * N_) + s) * 3;
    float qx = qp[0], qy = qp[1], qz = qp[2];
    const float r2 = 0.01f;   // f32(0.1(f64)^2) == 0.01f exactly
    unsigned long long lmask = (1ull << lane) - 1ull;

    int cx = (int)(qx * 9.999f), cy = (int)(qy * 9.999f), cz = (int)(qz * 9.999f);
    int xlo = max(cx - 1, 0), xhi = min(cx + 1, GD - 1);
    int ylo = max(cy - 1, 0), yhi = min(cy + 1, GD - 1);
    int zlo = max(cz - 1, 0), zhi = min(cz + 1, GD - 1);
    int nx = xhi - xlo + 1, ny = yhi - ylo + 1;
    int nruns = nx * ny;                     // <= 9 contiguous z-runs

    const int* cs = cellStart + b * (NCP + 1);
    int start = 0, len = 0;
    if (lane < nruns) {
        int xi = xlo + lane / ny, yi = ylo + lane % ny;
        int cbase = (xi * GD + yi) * GD;
        start = cs[cbase + zlo];
        len = cs[cbase + zhi + 1] - start;
    }
    int v = len;
    for (int d = 1; d < 64; d <<= 1) {
        int o = __shfl_up(v, d);
        if (lane >= d) v += o;
    }
    int T = __shfl(v, 63);
    int excl = v - len;
    int ro[9], rs[9];
#pragma unroll
    for (int rr = 0; rr < 9; ++rr) {
        int oo = __shfl(excl, rr);
        int ss = __shfl(start, rr);
        bool live = rr < nruns;
        ro[rr] = live ? oo : 0x7fffffff;
        rs[rr] = live ? (ss - oo) : 0;
    }

    int cnt = 0;
    for (int k0 = 0; k0 < T; k0 += 64) {
        int pos = k0 + lane;
        bool valid = pos < T;
        int basev = rs[0];
#pragma unroll
        for (int rr = 1; rr < 9; ++rr)
            basev = (ro[rr] <= pos) ? rs[rr] : basev;
        float px = 1.e30f, py = 1.e30f, pz = 1.e30f;
        int pid = 0;
        if (valid) {
            int src = basev + pos;
            const float* pp = sortedXyz + ((size_t)(b * N_) + src) * 3;
            px = pp[0]; py = pp[1]; pz = pp[2];
            pid = sortedId[b * N_ + src];
        }
        // bit-exact reference arithmetic: no FMA, (dx^2+dy^2)+dz^2
        float dx = __fsub_rn(px, qx);
        float dy = __fsub_rn(py, qy);
        float dz = __fsub_rn(pz, qz);
        float d2 = __fadd_rn(__fadd_rn(__fmul_rn(dx, dx), __fmul_rn(dy, dy)),
                             __fmul_rn(dz, dz));
        bool pred = valid && (d2 < r2);
        unsigned long long m = __ballot(pred);
        if (pred) {
            int p = cnt + __builtin_popcountll(m & lmask);
            if (p < 128) shbuf[w][p] = pid;
        }
        cnt += __builtin_popcountll(m);
    }

    // in-register bitonic sort ascending (INF pad); 64-wide fast path (cnt<=64,
    // ~99% of waves, wave-uniform branch), 128-wide fallback.
    const int INF = 0x7fffffff;
    int v0 = (lane < cnt && lane < 128) ? shbuf[w][lane] : INF;
    if (cnt <= 64) {
#pragma unroll
        for (int k = 2; k <= 64; k <<= 1) {
#pragma unroll
            for (int j = k >> 1; j >= 1; j >>= 1) {
                int p0 = __shfl_xor(v0, j);
                bool lower = (lane & j) == 0;
                bool asc = (lane & k) == 0;   // k==64: all ascending
                v0 = (lower == asc) ? min(v0, p0) : max(v0, p0);
            }
        }
    } else {
        int v1 = (lane + 64 < cnt) ? shbuf[w][lane + 64] : INF;
#pragma unroll
        for (int k = 2; k <= 128; k <<= 1) {
#pragma unroll
            for (int j = 64; j >= 1; j >>= 1) {
                if (j > (k >> 1)) continue;
                if (j == 64) {
                    int lo = min(v0, v1), hi = max(v0, v1);
                    v0 = lo; v1 = hi;
                } else {
                    int p0 = __shfl_xor(v0, j), p1 = __shfl_xor(v1, j);
                    bool lower = (lane & j) == 0;
                    bool asc0 = (lane & k) == 0;
                    bool asc1 = ((lane + 64) & k) == 0;
                    v0 = (lower == asc0) ? min(v0, p0) : max(v0, p0);
                    v1 = (lower == asc1) ? min(v1, p1) : max(v1, p1);
                }
            }
        }
    }
    int first = __shfl(v0, 0);               // self always in ball -> cnt>=1
    int cl = lane & 15, kq = lane >> 4;
    int sv0 = __shfl(v0, cl);
    int sv1 = __shfl(v0, cl + 16);
    int i0 = (cl < cnt) ? sv0 : first;
    int i1 = (cl + 16 < cnt) ? sv1 : first;

    // ---------------- MLP ----------------
    // B fragments: features hi only (lo dropped: error ~1e-3 << threshold)
    bf16x8 bh[2][2];
#pragma unroll
    for (int nt = 0; nt < 2; ++nt) {
        int i = nt ? i1 : i0;
        size_t rowoff = ((size_t)(b * N_ + i)) * C_ + kq * 8;
#pragma unroll
        for (int kt = 0; kt < 2; ++kt)
            bh[nt][kt] = *reinterpret_cast<const bf16x8*>(fT_hi + rowoff + kt * 32);
    }
    bf16x8 brel[2];
#pragma unroll
    for (int nt = 0; nt < 2; ++nt) {
        int i = nt ? i1 : i0;
        bf16x8 vv = (bf16x8)(short)0;
        if (kq == 0) {
            const float* p = xyz + ((size_t)(b * N_) + i) * 3;
            vv[0] = (short)f2bf(__fsub_rn(p[0], qx));
            vv[1] = (short)f2bf(__fsub_rn(p[1], qy));
            vv[2] = (short)f2bf(__fsub_rn(p[2], qz));
        }
        brel[nt] = vv;
    }

    // Layer 1: H'(64x32) = (W1h+W1l)(64x96) * Xhi(96x32)   (rows permrow'd)
    f32x4 acc[4][2];
#pragma unroll
    for (int mt = 0; mt < 4; ++mt) {
        int bn = ((mt >> 1) << 5) + kq * 8 + ((mt & 1) << 2);
        f32x4 bias = *reinterpret_cast<const f32x4*>(b1 + bn);
        acc[mt][0] = bias;
        acc[mt][1] = bias;
    }
#pragma unroll
    for (int mt = 0; mt < 4; ++mt) {
        bf16x8 ah0 = *reinterpret_cast<const bf16x8*>(W1x_hi + (mt * 3 + 0) * 512 + lane * 8);
        bf16x8 ah1 = *reinterpret_cast<const bf16x8*>(W1x_hi + (mt * 3 + 1) * 512 + lane * 8);
        bf16x8 ah2 = *reinterpret_cast<const bf16x8*>(W1x_hi + (mt * 3 + 2) * 512 + lane * 8);
        bf16x8 al0 = *reinterpret_cast<const bf16x8*>(W1x_lo + (mt * 3 + 0) * 512 + lane * 8);
        bf16x8 al1 = *reinterpret_cast<const bf16x8*>(W1x_lo + (mt * 3 + 1) * 512 + lane * 8);
#pragma unroll
        for (int nt = 0; nt < 2; ++nt) {
            f32x4 a = acc[mt][nt];
            a = MFMA32(ah0, bh[nt][0], a, 0, 0, 0);
            a = MFMA32(al0, bh[nt][0], a, 0, 0, 0);
            a = MFMA32(ah1, bh[nt][1], a, 0, 0, 0);
            a = MFMA32(al1, bh[nt][1], a, 0, 0, 0);
            a = MFMA32(ah2, brel[nt], a, 0, 0, 0);
            acc[mt][nt] = a;
        }
    }

    // relu + hi/lo split IN-LANE -> L2 x32 B fragments (permrow makes this direct)
    bf16x8 p2h[2][2], p2l[2][2];
#pragma unroll
    for (int kt = 0; kt < 2; ++kt)
#pragma unroll
        for (int nt = 0; nt < 2; ++nt) {
            bf16x8 hh, hl;
#pragma unroll
            for (int i = 0; i < 4; ++i) {
                float va = fmaxf(acc[kt * 2 + 0][nt][i], 0.f);
                float vb = fmaxf(acc[kt * 2 + 1][nt][i], 0.f);
                unsigned short ha = f2bf(va), hb = f2bf(vb);
                hh[i]     = (short)ha;
                hh[4 + i] = (short)hb;
                hl[i]     = (short)f2bf(va - bf2f(ha));
                hl[4 + i] = (short)f2bf(vb - bf2f(hb));
            }
            p2h[kt][nt] = hh;
            p2l[kt][nt] = hl;
        }

    // Layer 2: Y(128x32) = W2'(128x64) * H'(64x32), two mt-halves
    float* ys = reinterpret_cast<float*>(&shbuf[0][0]);
#pragma unroll
    for (int hm = 0; hm < 2; ++hm) {
        f32x4 acc2[4][2];
#pragma unroll
        for (int mt4 = 0; mt4 < 4; ++mt4) {
            f32x4 bias = *reinterpret_cast<const f32x4*>(b2 + (hm * 4 + mt4) * 16 + kq * 4);
            acc2[mt4][0] = bias;
            acc2[mt4][1] = bias;
        }
#pragma unroll
        for (int mt4 = 0; mt4 < 4; ++mt4) {
            int mt2 = hm * 4 + mt4;
#pragma unroll
            for (int kt = 0; kt < 2; ++kt) {
                bf16x8 ah = *reinterpret_cast<const bf16x8*>(W2x_hi + (mt2 * 2 + kt) * 512 + lane * 8);
                bf16x8 al = *reinterpret_cast<const bf16x8*>(W2x_lo + (mt2 * 2 + kt) * 512 + lane * 8);
#pragma unroll
                for (int nt = 0; nt < 2; ++nt) {
                    f32x4 a = acc2[mt4][nt];
                    a = MFMA32(ah, p2h[kt][nt], a, 0, 0, 0);
                    a = MFMA32(ah, p2l[kt][nt], a, 0, 0, 0);
                    a = MFMA32(al, p2h[kt][nt], a, 0, 0, 0);
                    acc2[mt4][nt] = a;
                }
            }
        }
#pragma unroll
        for (int mt4 = 0; mt4 < 4; ++mt4) {
            f32x4 m;
#pragma unroll
            for (int r = 0; r < 4; ++r)
                m[r] = fmaxf(fmaxf(acc2[mt4][0][r], 0.f), fmaxf(acc2[mt4][1][r], 0.f));
#pragma unroll
            for (int mask = 1; mask <= 8; mask <<= 1)
#pragma unroll
                for (int r = 0; r < 4; ++r)
                    m[r] = fmaxf(m[r], __shfl_xor(m[r], mask));
            if (cl == 0)
                *reinterpret_cast<f32x4*>(ys + w * 128 + (hm * 4 + mt4) * 16 + kq * 4) = m;
        }
    }

    // ---------------- cooperative transposed store ----------------
    __syncthreads();
    if (t < 128) {
        int o = t;
        int bb = blockIdx.x >> 9;
        int s0 = (blockIdx.x & 511) * 4;
        float4 vv = { ys[0 * 128 + o], ys[1 * 128 + o], ys[2 * 128 + o], ys[3 * 128 + o] };
        *reinterpret_cast<float4*>(out + NXYZ + ((size_t)(bb * H2_ + o)) * NPOINT + s0) = vv;
    }
}

// ================================================================ launcher
extern "C" void kernel_launch(void* const* d_in, const int* in_sizes, int n_in,
                              void* d_out, int out_size, void* d_ws, size_t ws_size,
                              hipStream_t stream)
{
    const float* xyz  = (const float*)d_in[0];
    const float* feat = (const float*)d_in[1];
    const float* W1   = (const float*)d_in[2];
    const float* b1   = (const float*)d_in[3];
    const float* W2   = (const float*)d_in[4];
    const float* b2   = (const float*)d_in[5];
    float* out = (float*)d_out;

    char* ws = (char*)d_ws;
    size_t off = 0;
    unsigned short* W1x_hi = (unsigned short*)(ws + off);  off += 6144 * 2;
    unsigned short* W1x_lo = (unsigned short*)(ws + off);  off += 6144 * 2;
    unsigned short* W2x_hi = (unsigned short*)(ws + off);  off += 8192 * 2;
    unsigned short* W2x_lo = (unsigned short*)(ws + off);  off += 8192 * 2;
    off = (off + 255) & ~(size_t)255;
    int* cellStart = (int*)(ws + off);                     off += (size_t)B_ * (NCP + 1) * 4;
    int* sortedId = (int*)(ws + off);                      off += (size_t)B_ * N_ * 4;
    float* sortedXyz = (float*)(ws + off);                 off += (size_t)B_ * N_ * 3 * 4;
    off = (off + 255) & ~(size_t)255;
    unsigned short* fT_hi = (unsigned short*)(ws + off);   off += (size_t)B_ * N_ * C_ * 2;    // 8 MiB

    grid_kernel<<<B_, 1024, 0, stream>>>(xyz, cellStart, sortedId, sortedXyz);
    prep_all_kernel<<<1080, 256, 0, stream>>>(
        xyz, feat, W1, W2, fT_hi, W1x_hi, W1x_lo, W2x_hi, W2x_lo, out);
    fused_kernel<<<NGROUP / 4, 256, 0, stream>>>(
        xyz, cellStart, sortedId, sortedXyz, fT_hi,
        W1x_hi, W1x_lo, b1, W2x_hi, W2x_lo, b2, out);
}